// Round 1
// baseline (662.289 us; speedup 1.0000x reference)
//
#include <hip/hip_runtime.h>
#include <hip/hip_bf16.h>
#include <stdint.h>

typedef unsigned short ushort_t;
typedef __bf16 bf16x8 __attribute__((ext_vector_type(8)));
typedef float f32x4 __attribute__((ext_vector_type(4)));

// ---------- helpers ----------

__device__ __forceinline__ ushort_t f2bf(float f) {
  // round-to-nearest-even bf16 (inputs are finite normals; no NaN handling needed)
  unsigned int u = __float_as_uint(f);
  u += 0x7FFFu + ((u >> 16) & 1u);
  return (ushort_t)(u >> 16);
}

typedef __attribute__((address_space(1))) void gvoid_t;
typedef __attribute__((address_space(3))) void lvoid_t;

__device__ __forceinline__ void async_cp16(const ushort_t* g, ushort_t* l) {
  // 16B/lane direct global->LDS DMA. LDS dest is wave-uniform base + lane*16.
  __builtin_amdgcn_global_load_lds((gvoid_t*)g, (lvoid_t*)l, 16, 0, 0);
}

// ---------- prep: x fp32 -> bf16 ----------

__global__ __launch_bounds__(256) void cvt_x_kernel(const float4* __restrict__ x,
                                                    ushort4* __restrict__ xb, int n4) {
  int i = blockIdx.x * blockDim.x + threadIdx.x;
  if (i >= n4) return;
  float4 v = x[i];
  ushort4 o;
  o.x = f2bf(v.x); o.y = f2bf(v.y); o.z = f2bf(v.z); o.w = f2bf(v.w);
  xb[i] = o;
}

// ---------- prep: weight quantize->dequant -> bf16 (exact in bf16) ----------

__device__ __forceinline__ float dq1(float w, float rs, float s, float z) {
  float q = rintf(w * rs + z);             // rintf = RNE, matches jnp.round
  q = fminf(fmaxf(q, 0.0f), 15.0f);
  return (q - z) * s;                      // (int in [-15,15]) * 2^e : exact in bf16
}

__global__ __launch_bounds__(256) void dequant_w_kernel(const float* __restrict__ w,
                                                        const float* __restrict__ sc,
                                                        const float* __restrict__ zp,
                                                        ushort_t* __restrict__ wq,
                                                        int total) {
  int base = (blockIdx.x * blockDim.x + threadIdx.x) * 8;
  if (base >= total) return;
  // group index: (o*K + i)/32 == o*(K/32) + i/32 exactly, since K % 32 == 0
  int gi = base >> 5;
  float s = sc[gi], z = zp[gi];
  float rs = 1.0f / s;                     // s = 2^e -> exact reciprocal
  const float4* w4 = (const float4*)(w + base);
  float4 a = w4[0], b = w4[1];
  ushort4 o0, o1;
  o0.x = f2bf(dq1(a.x, rs, s, z)); o0.y = f2bf(dq1(a.y, rs, s, z));
  o0.z = f2bf(dq1(a.z, rs, s, z)); o0.w = f2bf(dq1(a.w, rs, s, z));
  o1.x = f2bf(dq1(b.x, rs, s, z)); o1.y = f2bf(dq1(b.y, rs, s, z));
  o1.z = f2bf(dq1(b.z, rs, s, z)); o1.w = f2bf(dq1(b.w, rs, s, z));
  ushort4* out4 = (ushort4*)(wq + base);
  out4[0] = o0; out4[1] = o1;
}

// ---------- GEMM: C[M,N] = Xbf[M,K] @ Wbf[N,K]^T + bias ----------
// 128x128 block tile, BK=64, 4 waves, each wave 64x64 via 4x4 of 16x16x32 MFMA.

#define BM 128
#define BN 128
#define BK 64

__global__ __launch_bounds__(256) void gemm_bt_bias_kernel(
    const ushort_t* __restrict__ A,   // [M,K] bf16 bits
    const ushort_t* __restrict__ B,   // [N,K] bf16 bits
    const float* __restrict__ bias,   // [N]
    float* __restrict__ C,            // [M,N] fp32
    int M, int N, int K) {
  __shared__ ushort_t sA[BM * BK];    // row-major [128][64], unpadded (global_load_lds order)
  __shared__ ushort_t sB[BN * BK];

  const int tid  = threadIdx.x;
  const int wave = tid >> 6;
  const int lane = tid & 63;
  const int bn = blockIdx.x, bm = blockIdx.y;
  const int m0 = bm * BM, n0 = bn * BN;
  const int wm = (wave >> 1) * 64, wn = (wave & 1) * 64;
  const int l15 = lane & 15, l4 = lane >> 4;

  f32x4 acc[4][4] = {};

  // staging: chunk = tid + it*256, 16B (8 bf16) per chunk; row = chunk/8, col8 = chunk%8
  const int srow = tid >> 3;
  const int sc8  = (tid & 7) * 8;

  for (int k0 = 0; k0 < K; k0 += BK) {
    __syncthreads();
#pragma unroll
    for (int it = 0; it < 4; ++it)
      async_cp16(A + (size_t)(m0 + srow + it * 32) * K + k0 + sc8,
                 &sA[(it * 256 + wave * 64) * 8]);
#pragma unroll
    for (int it = 0; it < 4; ++it)
      async_cp16(B + (size_t)(n0 + srow + it * 32) * K + k0 + sc8,
                 &sB[(it * 256 + wave * 64) * 8]);
    __syncthreads();   // compiler emits s_waitcnt vmcnt(0) before s_barrier

#pragma unroll
    for (int kk = 0; kk < BK; kk += 32) {
      bf16x8 af[4], bfr[4];
#pragma unroll
      for (int t = 0; t < 4; ++t)
        af[t] = *(const bf16x8*)&sA[(wm + t * 16 + l15) * BK + kk + l4 * 8];
#pragma unroll
      for (int t = 0; t < 4; ++t)
        bfr[t] = *(const bf16x8*)&sB[(wn + t * 16 + l15) * BK + kk + l4 * 8];
#pragma unroll
      for (int mt = 0; mt < 4; ++mt)
#pragma unroll
        for (int nt = 0; nt < 4; ++nt)
          acc[mt][nt] = __builtin_amdgcn_mfma_f32_16x16x32_bf16(
              af[mt], bfr[nt], acc[mt][nt], 0, 0, 0);
    }
  }

  // epilogue: C/D layout col = lane&15, row = (lane>>4)*4 + reg
  const int ccol = n0 + wn + l15;
  const int crow = m0 + wm + l4 * 4;
#pragma unroll
  for (int nt = 0; nt < 4; ++nt) {
    float bv = bias[ccol + nt * 16];
#pragma unroll
    for (int mt = 0; mt < 4; ++mt) {
#pragma unroll
      for (int r = 0; r < 4; ++r)
        C[(size_t)(crow + mt * 16 + r) * N + ccol + nt * 16] = acc[mt][nt][r] + bv;
    }
  }
}

// ---------- launch ----------

extern "C" void kernel_launch(void* const* d_in, const int* in_sizes, int n_in,
                              void* d_out, int out_size, void* d_ws, size_t ws_size,
                              hipStream_t stream) {
  const float* x    = (const float*)d_in[0];  // [M,K] fp32
  const float* w    = (const float*)d_in[1];  // [N,K] fp32
  const float* bias = (const float*)d_in[2];  // [N]
  const float* sc   = (const float*)d_in[3];  // [N, K/32]
  const float* zp   = (const float*)d_in[4];  // [N, K/32]
  float* out = (float*)d_out;

  const int N = in_sizes[2];       // 4096
  const int K = in_sizes[1] / N;   // 4096
  const int M = in_sizes[0] / K;   // 8192

  ushort_t* xb = (ushort_t*)d_ws;                 // M*K bf16 = 64 MB
  ushort_t* wq = xb + (size_t)M * K;              // N*K bf16 = 32 MB

  int n4 = (M * K) / 4;
  cvt_x_kernel<<<(n4 + 255) / 256, 256, 0, stream>>>((const float4*)x, (ushort4*)xb, n4);

  int wthreads = (N * K) / 8;
  dequant_w_kernel<<<(wthreads + 255) / 256, 256, 0, stream>>>(w, sc, zp, wq, N * K);

  dim3 grid(N / BN, M / BM);
  gemm_bt_bias_kernel<<<grid, 256, 0, stream>>>(xb, wq, bias, out, M, N, K);
}

// Round 2
// 607.060 us; speedup vs baseline: 1.0910x; 1.0910x over previous
//
#include <hip/hip_runtime.h>
#include <hip/hip_bf16.h>
#include <stdint.h>

typedef unsigned short ushort_t;
typedef __bf16 bf16x8 __attribute__((ext_vector_type(8)));
typedef float f32x4 __attribute__((ext_vector_type(4)));

// ---------- helpers ----------

__device__ __forceinline__ ushort_t f2bf(float f) {
  // round-to-nearest-even bf16 (inputs are finite normals; no NaN handling needed)
  unsigned int u = __float_as_uint(f);
  u += 0x7FFFu + ((u >> 16) & 1u);
  return (ushort_t)(u >> 16);
}

typedef __attribute__((address_space(1))) void gvoid_t;
typedef __attribute__((address_space(3))) void lvoid_t;

__device__ __forceinline__ void async_cp16(const ushort_t* g, ushort_t* l) {
  // 16B/lane direct global->LDS DMA. LDS dest is wave-uniform base + lane*16.
  __builtin_amdgcn_global_load_lds((gvoid_t*)g, (lvoid_t*)l, 16, 0, 0);
}

// ---------- prep: x fp32 -> bf16 ----------

__global__ __launch_bounds__(256) void cvt_x_kernel(const float4* __restrict__ x,
                                                    ushort4* __restrict__ xb, int n4) {
  int i = blockIdx.x * blockDim.x + threadIdx.x;
  if (i >= n4) return;
  float4 v = x[i];
  ushort4 o;
  o.x = f2bf(v.x); o.y = f2bf(v.y); o.z = f2bf(v.z); o.w = f2bf(v.w);
  xb[i] = o;
}

// ---------- prep: weight quantize->dequant -> bf16 (exact in bf16) ----------

__device__ __forceinline__ float dq1(float w, float rs, float s, float z) {
  float q = rintf(w * rs + z);             // rintf = RNE, matches jnp.round
  q = fminf(fmaxf(q, 0.0f), 15.0f);
  return (q - z) * s;                      // (int in [-15,15]) * 2^e : exact in bf16
}

__global__ __launch_bounds__(256) void dequant_w_kernel(const float* __restrict__ w,
                                                        const float* __restrict__ sc,
                                                        const float* __restrict__ zp,
                                                        ushort_t* __restrict__ wq,
                                                        int total) {
  int base = (blockIdx.x * blockDim.x + threadIdx.x) * 8;
  if (base >= total) return;
  // group index: (o*K + i)/32 == o*(K/32) + i/32 exactly, since K % 32 == 0
  int gi = base >> 5;
  float s = sc[gi], z = zp[gi];
  float rs = 1.0f / s;                     // s = 2^e -> exact reciprocal
  const float4* w4 = (const float4*)(w + base);
  float4 a = w4[0], b = w4[1];
  ushort4 o0, o1;
  o0.x = f2bf(dq1(a.x, rs, s, z)); o0.y = f2bf(dq1(a.y, rs, s, z));
  o0.z = f2bf(dq1(a.z, rs, s, z)); o0.w = f2bf(dq1(a.w, rs, s, z));
  o1.x = f2bf(dq1(b.x, rs, s, z)); o1.y = f2bf(dq1(b.y, rs, s, z));
  o1.z = f2bf(dq1(b.z, rs, s, z)); o1.w = f2bf(dq1(b.w, rs, s, z));
  ushort4* out4 = (ushort4*)(wq + base);
  out4[0] = o0; out4[1] = o1;
}

// ---------- GEMM: C[M,N] = Xbf[M,K] @ Wbf[N,K]^T + bias ----------
// 128x128 block tile, BK=64, 4 waves, each wave 64x64 via 4x4 of 16x16x32 MFMA.
// LDS layout: [row][8 chunks of 8 bf16], physical chunk col = logical ^ (row&7)
// (XOR swizzle applied at the *global source address* so global_load_lds's
// lane-contiguous LDS write order is preserved). Fragment ds_read_b128 then
// lands 2 lanes per 4-bank group = conflict-free (m136: 2-way is free).

#define BM 128
#define BN 128
#define BK 64

__global__ __launch_bounds__(256) void gemm_bt_bias_kernel(
    const ushort_t* __restrict__ A,   // [M,K] bf16 bits
    const ushort_t* __restrict__ B,   // [N,K] bf16 bits
    const float* __restrict__ bias,   // [N]
    float* __restrict__ C,            // [M,N] fp32
    int M, int N, int K) {
  __shared__ ushort_t sA[BM * BK];
  __shared__ ushort_t sB[BN * BK];

  const int tid  = threadIdx.x;
  const int wave = tid >> 6;
  const int lane = tid & 63;
  const int bn = blockIdx.x, bm = blockIdx.y;
  const int m0 = bm * BM, n0 = bn * BN;
  const int wm = (wave >> 1) * 64, wn = (wave & 1) * 64;
  const int l15 = lane & 15, l4 = lane >> 4;

  f32x4 acc[4][4] = {};

  // staging: physical chunk = tid + it*256 -> row = it*32 + tid/8, pcol = tid&7.
  // That physical slot must hold logical col = pcol ^ (row&7); row&7 = (tid>>3)&7.
  const int srow = tid >> 3;
  const int gcol = ((tid & 7) ^ ((tid >> 3) & 7)) * 8;   // swizzled source col (elems)

  // fragment read: row = wm + t*16 + l15 -> row&7 = l15&7
  const int xa = l15 & 7;

  for (int k0 = 0; k0 < K; k0 += BK) {
    __syncthreads();
#pragma unroll
    for (int it = 0; it < 4; ++it)
      async_cp16(A + (size_t)(m0 + srow + it * 32) * K + k0 + gcol,
                 &sA[(it * 256 + wave * 64) * 8]);
#pragma unroll
    for (int it = 0; it < 4; ++it)
      async_cp16(B + (size_t)(n0 + srow + it * 32) * K + k0 + gcol,
                 &sB[(it * 256 + wave * 64) * 8]);
    __syncthreads();   // compiler emits s_waitcnt vmcnt(0) before s_barrier

#pragma unroll
    for (int kk = 0; kk < BK; kk += 32) {
      bf16x8 af[4], bfr[4];
#pragma unroll
      for (int t = 0; t < 4; ++t) {
        int pc = (((kk >> 3) + l4) ^ xa) << 3;             // swizzled physical col
        af[t] = *(const bf16x8*)&sA[(wm + t * 16 + l15) * BK + pc];
      }
#pragma unroll
      for (int t = 0; t < 4; ++t) {
        int pc = (((kk >> 3) + l4) ^ xa) << 3;
        bfr[t] = *(const bf16x8*)&sB[(wn + t * 16 + l15) * BK + pc];
      }
#pragma unroll
      for (int mt = 0; mt < 4; ++mt)
#pragma unroll
        for (int nt = 0; nt < 4; ++nt)
          acc[mt][nt] = __builtin_amdgcn_mfma_f32_16x16x32_bf16(
              af[mt], bfr[nt], acc[mt][nt], 0, 0, 0);
    }
  }

  // epilogue: C/D layout col = lane&15, row = (lane>>4)*4 + reg
  const int ccol = n0 + wn + l15;
  const int crow = m0 + wm + l4 * 4;
#pragma unroll
  for (int nt = 0; nt < 4; ++nt) {
    float bv = bias[ccol + nt * 16];
#pragma unroll
    for (int mt = 0; mt < 4; ++mt) {
#pragma unroll
      for (int r = 0; r < 4; ++r)
        C[(size_t)(crow + mt * 16 + r) * N + ccol + nt * 16] = acc[mt][nt][r] + bv;
    }
  }
}

// ---------- launch ----------

extern "C" void kernel_launch(void* const* d_in, const int* in_sizes, int n_in,
                              void* d_out, int out_size, void* d_ws, size_t ws_size,
                              hipStream_t stream) {
  const float* x    = (const float*)d_in[0];  // [M,K] fp32
  const float* w    = (const float*)d_in[1];  // [N,K] fp32
  const float* bias = (const float*)d_in[2];  // [N]
  const float* sc   = (const float*)d_in[3];  // [N, K/32]
  const float* zp   = (const float*)d_in[4];  // [N, K/32]
  float* out = (float*)d_out;

  const int N = in_sizes[2];       // 4096
  const int K = in_sizes[1] / N;   // 4096
  const int M = in_sizes[0] / K;   // 8192

  ushort_t* xb = (ushort_t*)d_ws;                 // M*K bf16 = 64 MB
  ushort_t* wq = xb + (size_t)M * K;              // N*K bf16 = 32 MB

  int n4 = (M * K) / 4;
  cvt_x_kernel<<<(n4 + 255) / 256, 256, 0, stream>>>((const float4*)x, (ushort4*)xb, n4);

  int wthreads = (N * K) / 8;
  dequant_w_kernel<<<(wthreads + 255) / 256, 256, 0, stream>>>(w, sc, zp, wq, N * K);

  dim3 grid(N / BN, M / BM);
  gemm_bt_bias_kernel<<<grid, 256, 0, stream>>>(xb, wq, bias, out, M, N, K);
}